// Round 9
// baseline (408.539 us; speedup 1.0000x reference)
//
#include <hip/hip_runtime.h>
#include <math.h>

// Problem constants
// B=4, H=W=64 -> L=4096, DIM=128, D_INNER=256, D_STATE=16, D_CONV=4, DT_RANK=8, NSLICES=16
#define LSEQ 4096

// Workspace layout (floats). Total ~140 MB (proven to fit)
// xz stored [b][l][p] (p-contiguous rows of 512): conv windows for ALL dirs are
// coalesced across the 256 d-lanes (row*512+d).
#define XZ_OFF   0ULL
#define XZ_SZ    (4ULL * 4096 * 512)
#define U_OFF    (XZ_OFF + XZ_SZ)
#define DIR_SZ   (4ULL * 256 * 4096)        // per direction
#define DELTA_OFF (U_OFF + 3ULL * DIR_SZ)   // delta; also holds wT_in before front runs
#define BC_OFF   (DELTA_OFF + 3ULL * DIR_SZ)
#define BC_SZ    (4ULL * 4096 * 32)         // per dir: B blocked [b][1024][16][4] then C blocked
#define WTIN_OFF DELTA_OFF                  // wT_in[128][512]; delta written later by front
#define WTOUT_OFF U_OFF                     // wT_out[256][128]; u dead after scan

__device__ __forceinline__ float sigmoidf_(float x) { return 1.0f / (1.0f + __expf(-x)); }
__device__ __forceinline__ float siluf_(float x)    { return x * sigmoidf_(x); }

// 2^x via HW transcendental.
__device__ __forceinline__ float fast_exp2_asm(float x) {
    float r;
    asm volatile("v_exp_f32 %0, %1\n\ts_nop 0" : "=v"(r) : "v"(x));
    return r;
}
#if defined(__has_builtin)
#if __has_builtin(__builtin_amdgcn_exp2f)
#define EXP2(x) __builtin_amdgcn_exp2f(x)
#else
#define EXP2(x) fast_exp2_asm(x)
#endif
#else
#define EXP2(x) fast_exp2_asm(x)
#endif

// softplus via HW exp2/log2: ln(1+e^x) = ln2 * log2(1 + 2^(x*log2e))
__device__ __forceinline__ float softplus_fast(float x) {
    float t = EXP2(1.44269504f * x);
    float r = 0.69314718f * __log2f(1.0f + t);
    return (x > 20.0f) ? x : r;
}

// dir permutation: scan-domain index j -> original-domain index
__device__ __forceinline__ int perm_idx(int dir, int j) {
    if (dir == 0) return j;
    if (dir == 1) return 4095 - j;
    return ((j & 15) << 8) | (j >> 4);   // slice: j = jj*16+s -> s*256+jj
}

// DPP cross-lane move (VALU pipe, no LDS). ctrl must be a literal.
#define DPP_MOV(x, ctrl) __int_as_float(__builtin_amdgcn_update_dpp(0, __float_as_int(x), (ctrl), 0xF, 0xF, true))

// ---------------------------------------------------------------------------
// K0: wT_in[c][p] = in_proj_w[p][c]   (128 x 512)
__global__ __launch_bounds__(256) void transpose_in_kernel(const float* __restrict__ w,
                                                           float* __restrict__ wT) {
    int idx = blockIdx.x * 256 + threadIdx.x;   // 65536
    int p = idx >> 7, c = idx & 127;
    wT[(size_t)c * 512 + p] = w[(size_t)p * 128 + c];
}

// ---------------------------------------------------------------------------
// K1: xz[b][l][p] = sum_c wT_in[c][p] * x_in[b][l][c]
__global__ __launch_bounds__(256) void inproj_kernel(const float* __restrict__ x,
                              const float* __restrict__ wT,
                              float* __restrict__ xz) {
    const int b = blockIdx.y;
    const int l0 = blockIdx.x * 16;
    __shared__ float xs[128 * 20];   // [c][l]
    for (int idx = threadIdx.x; idx < 16 * 128; idx += 256) {
        int li = idx >> 7, c = idx & 127;
        xs[c * 20 + li] = x[((size_t)(b * 4096 + l0 + li)) * 128 + c];
    }
    __syncthreads();
    const int p0 = (threadIdx.x & 127) * 4;
    const int g8 = (threadIdx.x >> 7) * 8;
    float acc[4][8];
    #pragma unroll
    for (int j = 0; j < 4; ++j)
        #pragma unroll
        for (int k = 0; k < 8; ++k) acc[j][k] = 0.0f;
    for (int c = 0; c < 128; ++c) {
        float4 wv = *(const float4*)(wT + (size_t)c * 512 + p0);
        const float* xp = xs + c * 20 + g8;
        float4 x0 = *(const float4*)(xp);
        float4 x1 = *(const float4*)(xp + 4);
        float xv[8] = {x0.x, x0.y, x0.z, x0.w, x1.x, x1.y, x1.z, x1.w};
        float wj[4] = {wv.x, wv.y, wv.z, wv.w};
        #pragma unroll
        for (int j = 0; j < 4; ++j)
            #pragma unroll
            for (int k = 0; k < 8; ++k) acc[j][k] += wj[j] * xv[k];
    }
    #pragma unroll
    for (int k = 0; k < 8; ++k) {
        float4 s; s.x = acc[0][k]; s.y = acc[1][k]; s.z = acc[2][k]; s.w = acc[3][k];
        *(float4*)(xz + ((size_t)(b * 4096 + l0 + g8 + k)) * 512 + p0) = s;
    }
}

// ---------------------------------------------------------------------------
// K2 (fused conv+silu+x_proj+dt, ALL dirs): per (32-scan-l tile, b, dir).
// r9: NO staging LDS — conv window loaded directly from global, coalesced across
// the 256 d-lanes (xz[row*512+d]). 2 barriers instead of 4. LDS 39 KB -> 4 blk/CU.
__global__ __launch_bounds__(256) void front_kernel(float* __restrict__ ws,
        const float* __restrict__ xw0, const float* __restrict__ xw1, const float* __restrict__ xw2,
        const float* __restrict__ dw0, const float* __restrict__ dw1, const float* __restrict__ dw2,
        const float* __restrict__ db0, const float* __restrict__ db1, const float* __restrict__ db2,
        const float* __restrict__ cw0, const float* __restrict__ cb0,
        const float* __restrict__ cw1, const float* __restrict__ cb1,
        const float* __restrict__ cw2, const float* __restrict__ cb2) {
    const int l0 = blockIdx.x * 32, b = blockIdx.y, dir = blockIdx.z;
    const float* xw = (dir == 0) ? xw0 : (dir == 1) ? xw1 : xw2;
    const float* dw = (dir == 0) ? dw0 : (dir == 1) ? dw1 : dw2;
    const float* db = (dir == 0) ? db0 : (dir == 1) ? db1 : db2;
    const float* cw = (dir == 0) ? cw0 : (dir == 1) ? cw1 : cw2;
    const float* cb = (dir == 0) ? cb0 : (dir == 1) ? cb1 : cb2;
    const float* xzb = ws + XZ_OFF + (size_t)b * 4096 * 512;
    float* ub      = ws + U_OFF + (size_t)dir * DIR_SZ + (size_t)b * 256 * 4096;
    float* deltab  = ws + DELTA_OFF + (size_t)dir * DIR_SZ + (size_t)b * 256 * 4096;
    float* Bf      = ws + BC_OFF + (size_t)dir * BC_SZ;
    float* Cf      = Bf + BC_SZ / 2;

    __shared__ float ut[32 * 264];   // swizzled u-tile [li][264]
    __shared__ float xd[40 * 33];

    const int d = threadIdx.x;

    // ---- conv window: direct coalesced loads (lane = d)
    float win[35];
    #pragma unroll
    for (int k = 0; k < 35; ++k) {
        int j = l0 - 3 + k;
        float v = 0.0f;
        if (j >= 0) {
            int row = (dir == 0) ? j : (dir == 1) ? (4095 - j) : (((j & 15) << 8) | (j >> 4));
            v = xzb[(size_t)row * 512 + d];
        }
        win[k] = v;
    }

    // ---- conv + silu
    const float w0 = cw[d * 4 + 0], w1 = cw[d * 4 + 1], w2 = cw[d * 4 + 2], w3 = cw[d * 4 + 3];
    const float bb = cb[d];
    float r[32];
    #pragma unroll
    for (int li = 0; li < 32; ++li)
        r[li] = siluf_(bb + w0 * win[li] + w1 * win[li + 1] + w2 * win[li + 2] + w3 * win[li + 3]);
    // u write (scan input), 128B contiguous per thread
    {
        float* urow = ub + (size_t)d * 4096 + l0;
        #pragma unroll
        for (int q = 0; q < 8; ++q) {
            float4 v; v.x = r[q*4]; v.y = r[q*4+1]; v.z = r[q*4+2]; v.w = r[q*4+3];
            *(float4*)(urow + q * 4) = v;
        }
    }
    // swizzled u-tile for the GEMM: ut[li][ 4*((d>>2)^(li&7)) + (d&3) ]
    #pragma unroll
    for (int li = 0; li < 32; ++li)
        ut[li * 264 + 4 * (((d >> 2) ^ (li & 7))) + (d & 3)] = r[li];
    __syncthreads();

    // ---- 40x256 GEMM: xd[40][32] = xw @ u-tile
    {
        const int rg = threadIdx.x >> 5;
        const int li = threadIdx.x & 31;
        float acc[5];
        #pragma unroll
        for (int j = 0; j < 5; ++j) acc[j] = 0.0f;
        const float* up = ut + li * 264;
        const int sw = (li & 7);
        #pragma unroll 2
        for (int c4 = 0; c4 < 64; ++c4) {
            float4 uv = *(const float4*)(up + 4 * (c4 ^ sw));
            const int c = 4 * (c4 ^ sw);
            #pragma unroll
            for (int j = 0; j < 5; ++j) {
                float4 wv = *(const float4*)(xw + (size_t)(rg * 5 + j) * 256 + c);
                acc[j] += wv.x * uv.x + wv.y * uv.y + wv.z * uv.z + wv.w * uv.w;
            }
        }
        #pragma unroll
        for (int j = 0; j < 5; ++j) xd[(rg * 5 + j) * 33 + li] = acc[j];
    }
    __syncthreads();

    // ---- B/C blocked writes (wave-coalesced) + delta
    {
        const int wv = threadIdx.x >> 6;
        const int lane = threadIdx.x & 63;
        const int n = lane >> 2, lq = lane & 3;
        #pragma unroll
        for (int j = 0; j < 2; ++j) {
            int l4 = (l0 >> 2) + j * 4 + wv;
            int li = (j * 4 + wv) * 4 + lq;
            size_t base = (((size_t)b * 1024 + l4) * 16 + n) * 4 + lq;
            Bf[base] = xd[(8 + n) * 33 + li];
            Cf[base] = xd[(24 + n) * 33 + li];
        }
    }
    {
        const int li = threadIdx.x & 31;
        float xr8[8];
        #pragma unroll
        for (int rr = 0; rr < 8; ++rr) xr8[rr] = xd[rr * 33 + li];
        #pragma unroll
        for (int k = 0; k < 32; ++k) {
            int dd = ((threadIdx.x + k * 256) >> 5);
            float4 wa = *(const float4*)(dw + dd * 8);
            float4 wb = *(const float4*)(dw + dd * 8 + 4);
            float acc = db[dd]
                + wa.x * xr8[0] + wa.y * xr8[1] + wa.z * xr8[2] + wa.w * xr8[3]
                + wb.x * xr8[4] + wb.y * xr8[5] + wb.z * xr8[6] + wb.w * xr8[7];
            deltab[(size_t)dd * 4096 + l0 + li] = softplus_fast(acc);
        }
    }
}

// ---------------------------------------------------------------------------
// K3: chunked selective scan. Block = (b,d,dir) row: 512 thr = 32 chunks x 16 states.
__global__ __launch_bounds__(512) void scan_kernel(float* __restrict__ ws,
                            const float* __restrict__ Al0, const float* __restrict__ Dp0,
                            const float* __restrict__ Al1, const float* __restrict__ Dp1,
                            const float* __restrict__ Al2, const float* __restrict__ Dp2) {
    const int d = blockIdx.x, b = blockIdx.y, dir = blockIdx.z;
    const float* Al = (dir == 0) ? Al0 : (dir == 1) ? Al1 : Al2;
    const float* Dp = (dir == 0) ? Dp0 : (dir == 1) ? Dp1 : Dp2;
    const int c = threadIdx.x >> 4;     // chunk 0..31
    const int n = threadIdx.x & 15;     // state 0..15
    const int qid = n >> 2;             // quad within chunk
    const float Ane = -1.44269504f * __expf(Al[d * 16 + n]);
    const float Dd = Dp[d];
    const float* urow = ws + U_OFF + (size_t)dir * DIR_SZ + ((size_t)(b * 256 + d)) * 4096;
    float* drow = ws + DELTA_OFF + (size_t)dir * DIR_SZ + ((size_t)(b * 256 + d)) * 4096;

    __shared__ float sdu[32 * 260];
    __shared__ float red[32 * 34];
    float* Psh = red;
    float* Ssh = red + 512;

    {
        const float4* d4 = (const float4*)drow;
        const float4* u4 = (const float4*)urow;
        for (int i = threadIdx.x; i < 1024; i += 512) {
            float4 dv = d4[i], uv = u4[i];
            int l = i * 4;
            float* p = sdu + (l >> 7) * 260 + (l & 127) * 2;
            float4 a, bq;
            a.x = dv.x; a.y = dv.x * uv.x; a.z = dv.y; a.w = dv.y * uv.y;
            bq.x = dv.z; bq.y = dv.z * uv.z; bq.z = dv.w; bq.w = dv.w * uv.w;
            *(float4*)(p) = a; *(float4*)(p + 4) = bq;
        }
    }
    __syncthreads();

    const float4* Bq = (const float4*)(ws + BC_OFF + (size_t)dir * BC_SZ)
                       + ((size_t)b * 1024 + c * 32) * 16 + n;
    const float4* Cq = (const float4*)(ws + BC_OFF + (size_t)dir * BC_SZ + BC_SZ / 2)
                       + ((size_t)b * 1024 + c * 32) * 16 + n;
    const float4* sp = (const float4*)(sdu + c * 260);

    // Pass 1: local scan + decay-sum
    float S = 0.0f, dsum = 0.0f;
    #pragma unroll 8
    for (int k4 = 0; k4 < 32; ++k4) {
        float4 a = sp[k4 * 2], bq = sp[k4 * 2 + 1];
        float4 Bv = Bq[(size_t)k4 * 16];
        float e0 = EXP2(Ane * a.x), e1 = EXP2(Ane * a.z);
        float e2 = EXP2(Ane * bq.x), e3 = EXP2(Ane * bq.z);
        dsum += (a.x + a.z) + (bq.x + bq.z);
        S = S * e0 + a.y * Bv.x;
        S = S * e1 + a.w * Bv.y;
        S = S * e2 + bq.y * Bv.z;
        S = S * e3 + bq.w * Bv.w;
    }
    Ssh[c * 16 + n] = S;
    Psh[c * 16 + n] = EXP2(Ane * dsum);
    __syncthreads();
    float h = 0.0f;
    for (int k = 0; k < c; ++k) h = h * Psh[k * 16 + n] + Ssh[k * 16 + n];
    __syncthreads();   // Psh/Ssh consumed; red becomes mat

    #define SCAN_STEP(t, ee, du, Bn, Cn) { \
        h = h * (ee) + (du) * (Bn); \
        float yp = h * (Cn); \
        yp += DPP_MOV(yp, 0xB1); \
        yp += DPP_MOV(yp, 0x4E); \
        red[(4 * (t) + qid) * 34 + c] = yp; }

    for (int g = 0; g < 16; ++g) {
        float4 a0 = sp[g * 4 + 0], a1 = sp[g * 4 + 1];
        float4 a2 = sp[g * 4 + 2], a3 = sp[g * 4 + 3];
        float4 Bv0 = Bq[(size_t)(g * 2) * 16], Bv1 = Bq[(size_t)(g * 2 + 1) * 16];
        float4 Cv0 = Cq[(size_t)(g * 2) * 16], Cv1 = Cq[(size_t)(g * 2 + 1) * 16];
        float e0 = EXP2(Ane * a0.x), e1 = EXP2(Ane * a0.z);
        float e2 = EXP2(Ane * a1.x), e3 = EXP2(Ane * a1.z);
        float e4 = EXP2(Ane * a2.x), e5 = EXP2(Ane * a2.z);
        float e6 = EXP2(Ane * a3.x), e7 = EXP2(Ane * a3.z);
        SCAN_STEP(0, e0, a0.y, Bv0.x, Cv0.x)
        SCAN_STEP(1, e1, a0.w, Bv0.y, Cv0.y)
        SCAN_STEP(2, e2, a1.y, Bv0.z, Cv0.z)
        SCAN_STEP(3, e3, a1.w, Bv0.w, Cv0.w)
        SCAN_STEP(4, e4, a2.y, Bv1.x, Cv1.x)
        SCAN_STEP(5, e5, a2.w, Bv1.y, Cv1.y)
        SCAN_STEP(6, e6, a3.y, Bv1.z, Cv1.z)
        SCAN_STEP(7, e7, a3.w, Bv1.w, Cv1.w)
        const int tt = n & 7;
        float q0 = red[(4 * tt + 0) * 34 + c];
        float q1 = red[(4 * tt + 1) * 34 + c];
        float q2 = red[(4 * tt + 2) * 34 + c];
        float q3 = red[(4 * tt + 3) * 34 + c];
        float y = (q0 + q1) + (q2 + q3);
        if (n < 8) {
            int gl = c * 128 + g * 8 + n;
            drow[perm_idx(dir, gl)] = y + Dd * urow[gl];
        }
    }
    #undef SCAN_STEP
}

// ---------------------------------------------------------------------------
// K3b: wT_out[d][o] = out_proj_w[o][d]  (runs AFTER scan; lives in dead U region)
__global__ __launch_bounds__(256) void transpose_w_kernel(const float* __restrict__ ow,
                                                          float* __restrict__ wT) {
    int idx = blockIdx.x * 256 + threadIdx.x;   // 32768
    int o = idx >> 8, d = idx & 255;
    wT[(size_t)d * 128 + o] = ow[(size_t)o * 256 + d];
}

// ---------------------------------------------------------------------------
// K4: y_total = silu(z)*(yf+yb+ys); out = wT^T @ y_total.
__global__ __launch_bounds__(256) void epilogue_kernel(const float* __restrict__ ws,
                                const float* __restrict__ wT,
                                float* __restrict__ out) {
    const int l0 = blockIdx.x * 16, b = blockIdx.y;
    __shared__ float yt[256 * 20];
    const float* yf = ws + DELTA_OFF;
    const float* yb = ws + DELTA_OFF + DIR_SZ;
    const float* ysd = ws + DELTA_OFF + 2 * DIR_SZ;
    const float* xzb = ws + XZ_OFF + (size_t)b * 4096 * 512;

    for (int idx = threadIdx.x; idx < 256 * 4; idx += 256) {
        int d = idx >> 2, q = (idx & 3) * 4;
        size_t ro = ((size_t)(b * 256 + d)) * 4096 + l0 + q;
        float4 vf = *(const float4*)(yf + ro);
        float4 vb = *(const float4*)(yb + ro);
        float4 vs = *(const float4*)(ysd + ro);
        float4 s; s.x = vf.x + vb.x + vs.x; s.y = vf.y + vb.y + vs.y;
        s.z = vf.z + vb.z + vs.z; s.w = vf.w + vb.w + vs.w;
        *(float4*)(yt + d * 20 + q) = s;
    }
    __syncthreads();
    {
        const int d = threadIdx.x;
        #pragma unroll 4
        for (int li = 0; li < 16; ++li) {
            float z = xzb[(size_t)(l0 + li) * 512 + 256 + d];
            yt[d * 20 + li] *= siluf_(z);
        }
    }
    __syncthreads();

    const int o0 = (threadIdx.x & 31) * 4;
    const int lp = (threadIdx.x >> 5) * 2;
    float a0[4], a1[4];
    #pragma unroll
    for (int j = 0; j < 4; ++j) { a0[j] = 0.0f; a1[j] = 0.0f; }
    #pragma unroll 4
    for (int d = 0; d < 256; ++d) {
        float4 w = *(const float4*)(wT + (size_t)d * 128 + o0);
        float2 y = *(const float2*)(yt + d * 20 + lp);
        a0[0] += w.x * y.x; a0[1] += w.y * y.x; a0[2] += w.z * y.x; a0[3] += w.w * y.x;
        a1[0] += w.x * y.y; a1[1] += w.y * y.y; a1[2] += w.z * y.y; a1[3] += w.w * y.y;
    }
    float4 s0; s0.x = a0[0]; s0.y = a0[1]; s0.z = a0[2]; s0.w = a0[3];
    float4 s1; s1.x = a1[0]; s1.y = a1[1]; s1.z = a1[2]; s1.w = a1[3];
    *(float4*)(out + ((size_t)(b * 4096 + l0 + lp)) * 128 + o0) = s0;
    *(float4*)(out + ((size_t)(b * 4096 + l0 + lp + 1)) * 128 + o0) = s1;
}

// ---------------------------------------------------------------------------
extern "C" void kernel_launch(void* const* d_in, const int* in_sizes, int n_in,
                              void* d_out, int out_size, void* d_ws, size_t ws_size,
                              hipStream_t stream) {
    const float* x_in = (const float*)d_in[0];
    const float* ipw  = (const float*)d_in[1];
    const float* cw[3]  = {(const float*)d_in[2],  (const float*)d_in[9],  (const float*)d_in[16]};
    const float* cb[3]  = {(const float*)d_in[3],  (const float*)d_in[10], (const float*)d_in[17]};
    const float* xpw[3] = {(const float*)d_in[4],  (const float*)d_in[11], (const float*)d_in[18]};
    const float* dtw[3] = {(const float*)d_in[5],  (const float*)d_in[12], (const float*)d_in[19]};
    const float* dtb[3] = {(const float*)d_in[6],  (const float*)d_in[13], (const float*)d_in[20]};
    const float* alog[3]= {(const float*)d_in[7],  (const float*)d_in[14], (const float*)d_in[21]};
    const float* dp[3]  = {(const float*)d_in[8],  (const float*)d_in[15], (const float*)d_in[22]};
    const float* ow   = (const float*)d_in[23];
    float* ws  = (float*)d_ws;
    float* out = (float*)d_out;

    transpose_in_kernel<<<dim3(256), 256, 0, stream>>>(ipw, ws + WTIN_OFF);
    inproj_kernel<<<dim3(256, 4), 256, 0, stream>>>(x_in, ws + WTIN_OFF, ws);
    front_kernel<<<dim3(128, 4, 3), 256, 0, stream>>>(ws,
        xpw[0], xpw[1], xpw[2], dtw[0], dtw[1], dtw[2], dtb[0], dtb[1], dtb[2],
        cw[0], cb[0], cw[1], cb[1], cw[2], cb[2]);
    scan_kernel<<<dim3(256, 4, 3), 512, 0, stream>>>(ws,
        alog[0], dp[0], alog[1], dp[1], alog[2], dp[2]);
    transpose_w_kernel<<<dim3(128), 256, 0, stream>>>(ow, ws + WTOUT_OFF);
    epilogue_kernel<<<dim3(256, 4), 256, 0, stream>>>(ws, ws + WTOUT_OFF, out);
}